// Round 1
// baseline (411.331 us; speedup 1.0000x reference)
//
#include <hip/hip_runtime.h>
#include <hip/hip_bf16.h>
#include <cstdint>

// Problem: B=384, S=128, E=512, H=4, D=128. out = softmax((x Wq)(x Wk)^T) (x Wv) Wo
// Strategy: f16 MFMA (16x16x32) everywhere, fp32 accumulate. Threshold is 2% of
// ref-max (0.1025); f16 keeps max error ~0.04 (bf16 would be ~0.11 - too risky).

#define EMB 512

typedef __attribute__((ext_vector_type(4))) float    f32x4;
typedef __attribute__((ext_vector_type(8))) _Float16 f16x8;

#define MFMA16(a, b, c) __builtin_amdgcn_mfma_f32_16x16x32_f16((a), (b), (c), 0, 0, 0)

// Swizzled LDS addressing: element (row,col) of a [128][stride] f16 tile lives at
// row*stride + (col ^ (((row>>2)&3)<<4)). Makes C-layout scalar writebacks
// conflict-free and b128 fragment reads conflict-ideal despite stride % 128B == 0.
__device__ __forceinline__ int swz128(int row, int col) {
    return row * 128 + (col ^ (((row >> 2) & 3) << 4));
}
__device__ __forceinline__ int swz64(int row, int col) {
    return row * 64 + (col ^ (((row >> 2) & 3) << 4));
}

__device__ __forceinline__ void gld_lds16(const _Float16* g, _Float16* l) {
    // async global->LDS, 16B/lane; LDS dest is wave-uniform base + lane*16
    __builtin_amdgcn_global_load_lds(
        (const __attribute__((address_space(1))) void*)g,
        (__attribute__((address_space(3))) void*)l, 16, 0, 0);
}

// Stage a [128 rows][64 cols] f16 tile (row stride 64) from global rows
// (grow0+n), cols [k0,k0+64). Swizzle is applied via the *source* address
// (16B-block kb holds global block kb ^ 2*g(n)), since global_load_lds lands
// linearly at base + lane*16.
__device__ __forceinline__ void stage64(_Float16* lds, const _Float16* gbase,
                                        int grow0, int k0, int wave, int lane) {
#pragma unroll
    for (int i = 0; i < 4; ++i) {
        int idx = wave * 256 + i * 64 + lane;   // 0..1023 16B-blocks
        int n   = idx >> 3;
        int kb  = (idx & 7) ^ (((n >> 2) & 3) << 1);
        gld_lds16(gbase + (grow0 + n) * EMB + k0 + kb * 8,
                  lds + wave * 2048 + i * 512);
    }
}

// C = Arows @ Bshared: M=128 (4 waves x 32 rows), N=128, K=512.
// A fragments direct-from-global (each row read once per block: L2-resident),
// shared B operand staged to LDS (read by all 4 waves).
__device__ __forceinline__ void proj_gemm(f32x4 acc[2][8],
        const _Float16* __restrict__ abase, int arow0,
        const _Float16* __restrict__ sbase, int srow0,
        _Float16* stageL, int wave, int lane) {
    const int l15 = lane & 15, quad = lane >> 4;
    for (int k0 = 0; k0 < EMB; k0 += 64) {
        stage64(stageL, sbase, srow0, k0, wave, lane);
        __syncthreads();                                  // drains vmcnt
#pragma unroll
        for (int ktl = 0; ktl < 2; ++ktl) {
            int kk = k0 + ktl * 32 + quad * 8;
            f16x8 a0 = *(const f16x8*)(abase + (arow0 + l15) * EMB + kk);
            f16x8 a1 = *(const f16x8*)(abase + (arow0 + 16 + l15) * EMB + kk);
#pragma unroll
            for (int nt = 0; nt < 8; ++nt) {
                int n = nt * 16 + l15;
                int c = (ktl * 32 + quad * 8) ^ (((n >> 2) & 3) << 4);
                f16x8 bb = *(const f16x8*)(stageL + n * 64 + c);
                acc[0][nt] = MFMA16(a0, bb, acc[0][nt]);
                acc[1][nt] = MFMA16(a1, bb, acc[1][nt]);
            }
        }
        __syncthreads();
    }
}

#define ZACC(A)                                   \
    _Pragma("unroll") for (int _i = 0; _i < 2; ++_i) \
    _Pragma("unroll") for (int _j = 0; _j < 8; ++_j) \
        A[_i][_j] = (f32x4){0.f, 0.f, 0.f, 0.f};

// ---------------- pack kernels ----------------
__global__ void k_cvt_x(const float* __restrict__ x, _Float16* __restrict__ xh) {
    long i = ((long)blockIdx.x * 256 + threadIdx.x) * 8;
    f32x4 a = *(const f32x4*)(x + i);
    f32x4 b = *(const f32x4*)(x + i + 4);
    f16x8 o;
    o[0] = (_Float16)a[0]; o[1] = (_Float16)a[1];
    o[2] = (_Float16)a[2]; o[3] = (_Float16)a[3];
    o[4] = (_Float16)b[0]; o[5] = (_Float16)b[1];
    o[6] = (_Float16)b[2]; o[7] = (_Float16)b[3];
    *(f16x8*)(xh + i) = o;
}

__global__ void k_transpose_w(const float* __restrict__ W, _Float16* __restrict__ Wt) {
    __shared__ float t[32][33];
    int tid = threadIdx.x;
    int tx = tid & 31, ty = tid >> 5;            // 32 x 8
    int k0 = blockIdx.x * 32, n0 = blockIdx.y * 32;
#pragma unroll
    for (int i = 0; i < 4; ++i)
        t[ty + i * 8][tx] = W[(k0 + ty + i * 8) * EMB + n0 + tx];
    __syncthreads();
#pragma unroll
    for (int i = 0; i < 4; ++i)
        Wt[(n0 + ty + i * 8) * EMB + k0 + tx] = (_Float16)t[tx][ty + i * 8];
}

// ---------------- fused attention: one block per (batch b, head h) ----------------
// MFMA 16x16x32 layouts (HW-verified per guide): A[m=lane&15][k=quad*8+j],
// B[k=quad*8+j][n=lane&15], C/D: col=lane&15, row=quad*4+reg.
__global__ __launch_bounds__(256, 2)
void k_attn(const _Float16* __restrict__ xh,
            const _Float16* __restrict__ Wqt, const _Float16* __restrict__ Wkt,
            const _Float16* __restrict__ Wvt,
            const float* __restrict__ bq, const float* __restrict__ bk,
            const float* __restrict__ bv,
            _Float16* __restrict__ attn) {
    __shared__ _Float16 RA[128 * 128];   // Q -> P -> O
    __shared__ _Float16 RB[128 * 128];   // (stage) -> K -> (stage) -> V^T
    const int tid = threadIdx.x, wave = tid >> 6, lane = tid & 63;
    const int l15 = lane & 15, quad = lane >> 4;
    const int b = blockIdx.x >> 2, h = blockIdx.x & 3;
    const int sRow0 = b * 128, wRow0 = h * 128;
    f32x4 acc[2][8];

    // ---- Q = x @ Wq[:,head] -> RA [s][d]
    ZACC(acc);
    proj_gemm(acc, xh, sRow0 + wave * 32, Wqt, wRow0, RB, wave, lane);
#pragma unroll
    for (int mt = 0; mt < 2; ++mt)
#pragma unroll
        for (int nt = 0; nt < 8; ++nt) {
            int col = nt * 16 + l15;
            float bias = bq[wRow0 + col];
#pragma unroll
            for (int r = 0; r < 4; ++r) {
                int row = wave * 32 + mt * 16 + quad * 4 + r;
                RA[swz128(row, col)] = (_Float16)(acc[mt][nt][r] + bias);
            }
        }

    // ---- K = x @ Wk[:,head] -> RB [t][d] (stages into RB front; writeback after
    //      proj_gemm's final barrier, so staging reads are complete)
    ZACC(acc);
    proj_gemm(acc, xh, sRow0 + wave * 32, Wkt, wRow0, RB, wave, lane);
#pragma unroll
    for (int mt = 0; mt < 2; ++mt)
#pragma unroll
        for (int nt = 0; nt < 8; ++nt) {
            int col = nt * 16 + l15;
            float bias = bk[wRow0 + col];
#pragma unroll
            for (int r = 0; r < 4; ++r) {
                int row = wave * 32 + mt * 16 + quad * 4 + r;
                RB[swz128(row, col)] = (_Float16)(acc[mt][nt][r] + bias);
            }
        }
    __syncthreads();

    // ---- scores = Q K^T (each wave owns 32 s-rows, all 128 t-cols)
    ZACC(acc);
#pragma unroll
    for (int kt = 0; kt < 4; ++kt) {
        int ca = kt * 32 + quad * 8;
        int rq = wave * 32 + l15;
        f16x8 q0 = *(const f16x8*)&RA[swz128(rq, ca)];
        f16x8 q1 = *(const f16x8*)&RA[swz128(rq + 16, ca)];
#pragma unroll
        for (int nt = 0; nt < 8; ++nt) {
            f16x8 kf = *(const f16x8*)&RB[swz128(nt * 16 + l15, ca)];
            acc[0][nt] = MFMA16(q0, kf, acc[0][nt]);
            acc[1][nt] = MFMA16(q1, kf, acc[1][nt]);
        }
    }
    // ---- softmax over t, in registers; a row lives in the 16 lanes of one quad
#pragma unroll
    for (int mt = 0; mt < 2; ++mt)
#pragma unroll
        for (int r = 0; r < 4; ++r) {
            float mx = acc[mt][0][r];
#pragma unroll
            for (int nt = 1; nt < 8; ++nt) mx = fmaxf(mx, acc[mt][nt][r]);
            mx = fmaxf(mx, __shfl_xor(mx, 1));
            mx = fmaxf(mx, __shfl_xor(mx, 2));
            mx = fmaxf(mx, __shfl_xor(mx, 4));
            mx = fmaxf(mx, __shfl_xor(mx, 8));
            float sm = 0.f;
#pragma unroll
            for (int nt = 0; nt < 8; ++nt) {
                float e = __expf(acc[mt][nt][r] - mx);
                acc[mt][nt][r] = e;
                sm += e;
            }
            sm += __shfl_xor(sm, 1);
            sm += __shfl_xor(sm, 2);
            sm += __shfl_xor(sm, 4);
            sm += __shfl_xor(sm, 8);
            float inv = 1.0f / sm;
#pragma unroll
            for (int nt = 0; nt < 8; ++nt) acc[mt][nt][r] *= inv;
        }
    __syncthreads();   // everyone done reading Q(RA)/K(RB)

    // ---- P -> RA (overwrites Q)
#pragma unroll
    for (int mt = 0; mt < 2; ++mt)
#pragma unroll
        for (int nt = 0; nt < 8; ++nt) {
            int col = nt * 16 + l15;
#pragma unroll
            for (int r = 0; r < 4; ++r) {
                int row = wave * 32 + mt * 16 + quad * 4 + r;
                RA[swz128(row, col)] = (_Float16)acc[mt][nt][r];
            }
        }

    // ---- V^T = Wv[:,head]^T @ x^T -> RB [d][t] (A rows from Wvt, B = x^T staged)
    ZACC(acc);
    proj_gemm(acc, Wvt, wRow0 + wave * 32, xh, sRow0, RB, wave, lane);
#pragma unroll
    for (int mt = 0; mt < 2; ++mt)
#pragma unroll
        for (int r = 0; r < 4; ++r) {
            int row = wave * 32 + mt * 16 + quad * 4 + r;   // row = d
            float bias = bv[wRow0 + row];
#pragma unroll
            for (int nt = 0; nt < 8; ++nt) {
                int col = nt * 16 + l15;                    // col = t
                RB[swz128(row, col)] = (_Float16)(acc[mt][nt][r] + bias);
            }
        }
    __syncthreads();   // P and V^T visible

    // ---- O = P @ V   (B[k=t][n=d] = V^T[d][t] = RB row d, contiguous t)
    ZACC(acc);
#pragma unroll
    for (int kt = 0; kt < 4; ++kt) {
        int ca = kt * 32 + quad * 8;
        int rp = wave * 32 + l15;
        f16x8 p0 = *(const f16x8*)&RA[swz128(rp, ca)];
        f16x8 p1 = *(const f16x8*)&RA[swz128(rp + 16, ca)];
#pragma unroll
        for (int nt = 0; nt < 8; ++nt) {
            f16x8 vf = *(const f16x8*)&RB[swz128(nt * 16 + l15, ca)];
            acc[0][nt] = MFMA16(p0, vf, acc[0][nt]);
            acc[1][nt] = MFMA16(p1, vf, acc[1][nt]);
        }
    }
    __syncthreads();   // all P/V reads done before overwriting RA

    // ---- O -> RA (f16), then coalesced 16B global stores
#pragma unroll
    for (int mt = 0; mt < 2; ++mt)
#pragma unroll
        for (int nt = 0; nt < 8; ++nt) {
            int col = nt * 16 + l15;
#pragma unroll
            for (int r = 0; r < 4; ++r) {
                int row = wave * 32 + mt * 16 + quad * 4 + r;
                RA[swz128(row, col)] = (_Float16)acc[mt][nt][r];
            }
        }
    __syncthreads();
#pragma unroll
    for (int i = 0; i < 8; ++i) {
        int idx = i * 256 + tid;
        int row = idx >> 4, col = (idx & 15) * 8;
        f16x8 v = *(const f16x8*)&RA[row * 128 + (col ^ (((row >> 2) & 3) << 4))];
        *(f16x8*)(attn + (long)(sRow0 + row) * EMB + wRow0 + col) = v;
    }
}

// ---------------- output projection: out = attn @ Wo + bo (fp32 out) ----------------
__global__ __launch_bounds__(256, 3)
void k_out(const _Float16* __restrict__ attn, const _Float16* __restrict__ Wot,
           const float* __restrict__ bo, float* __restrict__ out) {
    __shared__ _Float16 SA[128 * 64];
    __shared__ _Float16 SB[128 * 64];
    const int tid = threadIdx.x, wave = tid >> 6, lane = tid & 63;
    const int l15 = lane & 15, quad = lane >> 4;
    const int m0 = (blockIdx.x >> 2) * 128, n0 = (blockIdx.x & 3) * 128;
    f32x4 acc[2][8];
    ZACC(acc);
    for (int k0 = 0; k0 < EMB; k0 += 64) {
        stage64(SA, attn, m0, k0, wave, lane);
        stage64(SB, Wot, n0, k0, wave, lane);
        __syncthreads();
#pragma unroll
        for (int ktl = 0; ktl < 2; ++ktl) {
            int ra = wave * 32 + l15;
            int cb = ktl * 32 + quad * 8;
            f16x8 a0 = *(const f16x8*)&SA[swz64(ra, cb)];
            f16x8 a1 = *(const f16x8*)&SA[swz64(ra + 16, cb)];
#pragma unroll
            for (int nt = 0; nt < 8; ++nt) {
                f16x8 bb = *(const f16x8*)&SB[swz64(nt * 16 + l15, cb)];
                acc[0][nt] = MFMA16(a0, bb, acc[0][nt]);
                acc[1][nt] = MFMA16(a1, bb, acc[1][nt]);
            }
        }
        __syncthreads();
    }
#pragma unroll
    for (int nt = 0; nt < 8; ++nt) {
        int col = n0 + nt * 16 + l15;
        float bias = bo[col];
#pragma unroll
        for (int mt = 0; mt < 2; ++mt)
#pragma unroll
            for (int r = 0; r < 4; ++r) {
                int row = m0 + wave * 32 + mt * 16 + quad * 4 + r;
                out[(long)row * EMB + col] = acc[mt][nt][r] + bias;
            }
    }
}

extern "C" void kernel_launch(void* const* d_in, const int* in_sizes, int n_in,
                              void* d_out, int out_size, void* d_ws, size_t ws_size,
                              hipStream_t stream) {
    const float* x  = (const float*)d_in[0];
    const float* Wq = (const float*)d_in[1];
    const float* bq = (const float*)d_in[2];
    const float* Wk = (const float*)d_in[3];
    const float* bk = (const float*)d_in[4];
    const float* Wv = (const float*)d_in[5];
    const float* bv = (const float*)d_in[6];
    const float* Wo = (const float*)d_in[7];
    const float* bo = (const float*)d_in[8];
    float* out = (float*)d_out;

    // workspace layout (f16): x 50.3MB | WqT WkT WvT WoT 0.5MB each | attn 50.3MB
    _Float16* xh   = (_Float16*)d_ws;
    _Float16* Wqt  = (_Float16*)((char*)d_ws + 50331648);
    _Float16* Wkt  = Wqt + 262144;
    _Float16* Wvt  = Wkt + 262144;
    _Float16* Wot  = Wvt + 262144;
    _Float16* attn = Wot + 262144;   // needs ws_size >= 102,760,448 B

    k_cvt_x<<<12288, 256, 0, stream>>>(x, xh);          // 25,165,824 elems / 8 / 256
    dim3 tg(16, 16);
    k_transpose_w<<<tg, 256, 0, stream>>>(Wq, Wqt);
    k_transpose_w<<<tg, 256, 0, stream>>>(Wk, Wkt);
    k_transpose_w<<<tg, 256, 0, stream>>>(Wv, Wvt);
    k_transpose_w<<<tg, 256, 0, stream>>>(Wo, Wot);
    k_attn<<<1536, 256, 0, stream>>>(xh, Wqt, Wkt, Wvt, bq, bk, bv, attn);
    k_out<<<1536, 256, 0, stream>>>(attn, Wot, bo, out);
}

// Round 2
// 385.284 us; speedup vs baseline: 1.0676x; 1.0676x over previous
//
#include <hip/hip_runtime.h>
#include <hip/hip_bf16.h>
#include <cstdint>

// B=384, S=128, E=512, H=4, D=128. out = softmax((x Wq)(x Wk)^T) (x Wv) Wo
// Round 2: decompose. k_qkv (big GEMM, V written transposed via operand swap)
// -> k_core (QK^T+softmax+PV, 5 barriers) -> k_out. f16 MFMA, fp32 accum.

#define EMB 512

typedef __attribute__((ext_vector_type(4))) float    f32x4;
typedef __attribute__((ext_vector_type(8))) _Float16 f16x8;

#define MFMA16(a, b, c) __builtin_amdgcn_mfma_f32_16x16x32_f16((a), (b), (c), 0, 0, 0)

// XOR swizzle: element (row,col) of a [*][stride] f16 tile at
// row*stride + (col ^ (((row>>2)&3)<<4)). C-writebacks conflict-free,
// b128 fragment reads conflict-ideal despite stride % 128B == 0.
__device__ __forceinline__ int swz128(int row, int col) {
    return row * 128 + (col ^ (((row >> 2) & 3) << 4));
}
__device__ __forceinline__ int swz64(int row, int col) {
    return row * 64 + (col ^ (((row >> 2) & 3) << 4));
}

__device__ __forceinline__ void gld_lds16(const _Float16* g, _Float16* l) {
    __builtin_amdgcn_global_load_lds(
        (const __attribute__((address_space(1))) void*)g,
        (__attribute__((address_space(3))) void*)l, 16, 0, 0);
}

// Stage a [128][64] f16 tile (row stride 64) from global rows grow0+n,
// cols [k0,k0+64), stride EMB. Swizzle applied via the source gather.
__device__ __forceinline__ void stage64(_Float16* lds, const _Float16* gbase,
                                        int grow0, int k0, int wave, int lane) {
#pragma unroll
    for (int i = 0; i < 4; ++i) {
        int idx = wave * 256 + i * 64 + lane;   // 16B-block id, 0..1023
        int n   = idx >> 3;
        int kb  = (idx & 7) ^ (((n >> 2) & 3) << 1);
        gld_lds16(gbase + (grow0 + n) * EMB + k0 + kb * 8,
                  lds + wave * 2048 + i * 512);
    }
}

// Stage a [128][128] f16 tile (row stride 128) from global rows grow0+n,
// cols [gcol0, gcol0+128), arbitrary global stride.
__device__ __forceinline__ void stage128(_Float16* lds, const _Float16* gbase,
                                         long grow0, int gstride, int gcol0,
                                         int wave, int lane) {
#pragma unroll
    for (int i = 0; i < 8; ++i) {
        int idx = wave * 512 + i * 64 + lane;   // 16B-block id, 0..2047
        int n   = idx >> 4;
        int kb  = (idx & 15) ^ (((n >> 2) & 3) << 1);
        gld_lds16(gbase + (grow0 + n) * gstride + gcol0 + kb * 8,
                  lds + wave * 4096 + i * 512);
    }
}

#define ZACC(A)                                   \
    _Pragma("unroll") for (int _i = 0; _i < 2; ++_i) \
    _Pragma("unroll") for (int _j = 0; _j < 8; ++_j) \
        A[_i][_j] = (f32x4){0.f, 0.f, 0.f, 0.f};

// ---------------- pack kernels ----------------
__global__ void k_cvt_x(const float* __restrict__ x, _Float16* __restrict__ xh) {
    long i = ((long)blockIdx.x * 256 + threadIdx.x) * 8;
    f32x4 a = *(const f32x4*)(x + i);
    f32x4 b = *(const f32x4*)(x + i + 4);
    f16x8 o;
    o[0] = (_Float16)a[0]; o[1] = (_Float16)a[1];
    o[2] = (_Float16)a[2]; o[3] = (_Float16)a[3];
    o[4] = (_Float16)b[0]; o[5] = (_Float16)b[1];
    o[6] = (_Float16)b[2]; o[7] = (_Float16)b[3];
    *(f16x8*)(xh + i) = o;
}

__global__ void k_transpose_w(const float* __restrict__ W, _Float16* __restrict__ Wt) {
    __shared__ float t[32][33];
    int tid = threadIdx.x;
    int tx = tid & 31, ty = tid >> 5;            // 32 x 8
    int k0 = blockIdx.x * 32, n0 = blockIdx.y * 32;
#pragma unroll
    for (int i = 0; i < 4; ++i)
        t[ty + i * 8][tx] = W[(k0 + ty + i * 8) * EMB + n0 + tx];
    __syncthreads();
#pragma unroll
    for (int i = 0; i < 4; ++i)
        Wt[(n0 + ty + i * 8) * EMB + k0 + tx] = (_Float16)t[tx][ty + i * 8];
}

// ---------------- QKV projection GEMM ----------------
// C[49152 x 1536] = xh @ [Wq|Wk|Wv]. 128x128 tiles: m-tile = one batch b,
// n-tile j: 0..3 -> Q head j, 4..7 -> K head j-4, 8..11 -> V head j-8.
// For V tiles the MFMA operands are SWAPPED (A<-weights, B<-x), so the
// accumulator is V^T[d][t] in C-layout -> store V transposed for free.
__global__ __launch_bounds__(256, 4)
void k_qkv(const _Float16* __restrict__ xh, const _Float16* __restrict__ Wqkvt,
           const float* __restrict__ bq, const float* __restrict__ bk,
           const float* __restrict__ bv,
           _Float16* __restrict__ qb, _Float16* __restrict__ kb,
           _Float16* __restrict__ vtb) {
    __shared__ _Float16 SA[128 * 64];
    __shared__ _Float16 SB[128 * 64];
    const int tid = threadIdx.x, wave = tid >> 6, lane = tid & 63;
    const int l15 = lane & 15, quad = lane >> 4;
    const int bi = blockIdx.x;
    const int bb = bi / 12, j = bi - bb * 12;
    const int m0 = bb * 128;
    const bool vswap = (j >= 8);
    const _Float16* As = vswap ? SB : SA;
    const _Float16* Bs = vswap ? SA : SB;
    f32x4 acc[2][8];
    ZACC(acc);
    for (int k0 = 0; k0 < EMB; k0 += 64) {
        stage64(SA, xh, m0, k0, wave, lane);
        stage64(SB, Wqkvt, j * 128, k0, wave, lane);
        __syncthreads();
#pragma unroll
        for (int ktl = 0; ktl < 2; ++ktl) {
            int cb = ktl * 32 + quad * 8;
            f16x8 a0 = *(const f16x8*)&As[swz64(wave * 32 + l15, cb)];
            f16x8 a1 = *(const f16x8*)&As[swz64(wave * 32 + 16 + l15, cb)];
#pragma unroll
            for (int nt = 0; nt < 8; ++nt) {
                f16x8 bbf = *(const f16x8*)&Bs[swz64(nt * 16 + l15, cb)];
                acc[0][nt] = MFMA16(a0, bbf, acc[0][nt]);
                acc[1][nt] = MFMA16(a1, bbf, acc[1][nt]);
            }
        }
        __syncthreads();
    }
    if (!vswap) {
        const float* bias = (j < 4) ? bq : bk;
        _Float16* dst = (j < 4) ? qb : kb;
        const int nc0 = (j & 3) * 128;
#pragma unroll
        for (int nt = 0; nt < 8; ++nt) {
            int col = nt * 16 + l15;
            float bv_ = bias[nc0 + col];
#pragma unroll
            for (int mt = 0; mt < 2; ++mt)
#pragma unroll
                for (int r = 0; r < 4; ++r) {
                    int row = wave * 32 + mt * 16 + quad * 4 + r;
                    dst[(long)(m0 + row) * EMB + nc0 + col] =
                        (_Float16)(acc[mt][nt][r] + bv_);
                }
        }
    } else {
        const int hv = j - 8;
        _Float16* dst = vtb + (long)(bb * 4 + hv) * 128 * 128;
#pragma unroll
        for (int mt = 0; mt < 2; ++mt)
#pragma unroll
            for (int r = 0; r < 4; ++r) {
                int d = wave * 32 + mt * 16 + quad * 4 + r;  // row = head-dim
                float bvv = bv[hv * 128 + d];
#pragma unroll
                for (int nt = 0; nt < 8; ++nt) {
                    int t = nt * 16 + l15;                   // col = token
                    dst[d * 128 + t] = (_Float16)(acc[mt][nt][r] + bvv);
                }
            }
    }
}

// ---------------- attention core: one block per (b,h) ----------------
// MFMA layouts: A[m=lane&15][k=quad*8+j], B[k=quad*8+j][n=lane&15],
// C/D: col=lane&15, row=quad*4+reg.
__global__ __launch_bounds__(256, 2)
void k_core(const _Float16* __restrict__ qb, const _Float16* __restrict__ kb,
            const _Float16* __restrict__ vtb, _Float16* __restrict__ attn) {
    __shared__ _Float16 SK[128 * 128];   // K -> P -> O
    __shared__ _Float16 SV[128 * 128];   // V^T
    const int tid = threadIdx.x, wave = tid >> 6, lane = tid & 63;
    const int l15 = lane & 15, quad = lane >> 4;
    const int b = blockIdx.x >> 2, h = blockIdx.x & 3;
    const int sRow0 = b * 128, wRow0 = h * 128;
    f32x4 acc[2][8];

    stage128(SK, kb, sRow0, EMB, wRow0, wave, lane);
    stage128(SV, vtb, (long)(b * 4 + h) * 128, 128, 0, wave, lane);
    __syncthreads();

    // ---- scores = Q K^T; Q fragments direct from global (each elem read once)
    ZACC(acc);
#pragma unroll
    for (int kt = 0; kt < 4; ++kt) {
        int ca = kt * 32 + quad * 8;
        const _Float16* qrow = qb + (long)(sRow0 + wave * 32 + l15) * EMB + wRow0 + ca;
        f16x8 q0 = *(const f16x8*)qrow;
        f16x8 q1 = *(const f16x8*)(qrow + 16 * EMB);
#pragma unroll
        for (int nt = 0; nt < 8; ++nt) {
            f16x8 kf = *(const f16x8*)&SK[swz128(nt * 16 + l15, ca)];
            acc[0][nt] = MFMA16(q0, kf, acc[0][nt]);
            acc[1][nt] = MFMA16(q1, kf, acc[1][nt]);
        }
    }
    // ---- softmax over t (row spread across the 16 lanes of a quad-row)
#pragma unroll
    for (int mt = 0; mt < 2; ++mt)
#pragma unroll
        for (int r = 0; r < 4; ++r) {
            float mx = acc[mt][0][r];
#pragma unroll
            for (int nt = 1; nt < 8; ++nt) mx = fmaxf(mx, acc[mt][nt][r]);
            mx = fmaxf(mx, __shfl_xor(mx, 1));
            mx = fmaxf(mx, __shfl_xor(mx, 2));
            mx = fmaxf(mx, __shfl_xor(mx, 4));
            mx = fmaxf(mx, __shfl_xor(mx, 8));
            float sm = 0.f;
#pragma unroll
            for (int nt = 0; nt < 8; ++nt) {
                float e = __expf(acc[mt][nt][r] - mx);
                acc[mt][nt][r] = e;
                sm += e;
            }
            sm += __shfl_xor(sm, 1);
            sm += __shfl_xor(sm, 2);
            sm += __shfl_xor(sm, 4);
            sm += __shfl_xor(sm, 8);
            float inv = 1.0f / sm;
#pragma unroll
            for (int nt = 0; nt < 8; ++nt) acc[mt][nt][r] *= inv;
        }
    __syncthreads();   // all QK^T reads of SK complete

    // ---- P -> SK (C-layout -> A-layout via LDS round trip)
#pragma unroll
    for (int mt = 0; mt < 2; ++mt)
#pragma unroll
        for (int nt = 0; nt < 8; ++nt) {
            int col = nt * 16 + l15;
#pragma unroll
            for (int r = 0; r < 4; ++r) {
                int row = wave * 32 + mt * 16 + quad * 4 + r;
                SK[swz128(row, col)] = (_Float16)acc[mt][nt][r];
            }
        }
    __syncthreads();

    // ---- O = P @ V  (B[k=t][n=d] = SV row d, contiguous t)
    ZACC(acc);
#pragma unroll
    for (int kt = 0; kt < 4; ++kt) {
        int ca = kt * 32 + quad * 8;
        int rp = wave * 32 + l15;
        f16x8 p0 = *(const f16x8*)&SK[swz128(rp, ca)];
        f16x8 p1 = *(const f16x8*)&SK[swz128(rp + 16, ca)];
#pragma unroll
        for (int nt = 0; nt < 8; ++nt) {
            f16x8 vf = *(const f16x8*)&SV[swz128(nt * 16 + l15, ca)];
            acc[0][nt] = MFMA16(p0, vf, acc[0][nt]);
            acc[1][nt] = MFMA16(p1, vf, acc[1][nt]);
        }
    }
    __syncthreads();   // all P reads done before overwriting SK

    // ---- O -> SK, then coalesced 16B stores
#pragma unroll
    for (int mt = 0; mt < 2; ++mt)
#pragma unroll
        for (int nt = 0; nt < 8; ++nt) {
            int col = nt * 16 + l15;
#pragma unroll
            for (int r = 0; r < 4; ++r) {
                int row = wave * 32 + mt * 16 + quad * 4 + r;
                SK[swz128(row, col)] = (_Float16)acc[mt][nt][r];
            }
        }
    __syncthreads();
#pragma unroll
    for (int i = 0; i < 8; ++i) {
        int idx = i * 256 + tid;
        int row = idx >> 4, col = (idx & 15) * 8;
        f16x8 v = *(const f16x8*)&SK[row * 128 + (col ^ (((row >> 2) & 3) << 4))];
        *(f16x8*)(attn + (long)(sRow0 + row) * EMB + wRow0 + col) = v;
    }
}

// ---------------- output projection: out = attn @ Wo + bo (fp32) ----------------
__global__ __launch_bounds__(256, 4)
void k_out(const _Float16* __restrict__ attn, const _Float16* __restrict__ Wot,
           const float* __restrict__ bo, float* __restrict__ out) {
    __shared__ _Float16 SA[128 * 64];
    __shared__ _Float16 SB[128 * 64];
    const int tid = threadIdx.x, wave = tid >> 6, lane = tid & 63;
    const int l15 = lane & 15, quad = lane >> 4;
    const int m0 = (blockIdx.x >> 2) * 128, n0 = (blockIdx.x & 3) * 128;
    f32x4 acc[2][8];
    ZACC(acc);
    for (int k0 = 0; k0 < EMB; k0 += 64) {
        stage64(SA, attn, m0, k0, wave, lane);
        stage64(SB, Wot, n0, k0, wave, lane);
        __syncthreads();
#pragma unroll
        for (int ktl = 0; ktl < 2; ++ktl) {
            int ra = wave * 32 + l15;
            int cb = ktl * 32 + quad * 8;
            f16x8 a0 = *(const f16x8*)&SA[swz64(ra, cb)];
            f16x8 a1 = *(const f16x8*)&SA[swz64(ra + 16, cb)];
#pragma unroll
            for (int nt = 0; nt < 8; ++nt) {
                f16x8 bb = *(const f16x8*)&SB[swz64(nt * 16 + l15, cb)];
                acc[0][nt] = MFMA16(a0, bb, acc[0][nt]);
                acc[1][nt] = MFMA16(a1, bb, acc[1][nt]);
            }
        }
        __syncthreads();
    }
#pragma unroll
    for (int nt = 0; nt < 8; ++nt) {
        int col = n0 + nt * 16 + l15;
        float bias = bo[col];
#pragma unroll
        for (int mt = 0; mt < 2; ++mt)
#pragma unroll
            for (int r = 0; r < 4; ++r) {
                int row = m0 + wave * 32 + mt * 16 + quad * 4 + r;
                out[(long)row * EMB + col] = acc[mt][nt][r] + bias;
            }
    }
}

extern "C" void kernel_launch(void* const* d_in, const int* in_sizes, int n_in,
                              void* d_out, int out_size, void* d_ws, size_t ws_size,
                              hipStream_t stream) {
    const float* x  = (const float*)d_in[0];
    const float* Wq = (const float*)d_in[1];
    const float* bq = (const float*)d_in[2];
    const float* Wk = (const float*)d_in[3];
    const float* bk = (const float*)d_in[4];
    const float* Wv = (const float*)d_in[5];
    const float* bv = (const float*)d_in[6];
    const float* Wo = (const float*)d_in[7];
    const float* bo = (const float*)d_in[8];
    float* out = (float*)d_out;

    // ws layout (bytes). attn ALIASES xh (xh dead after k_qkv). Peak ~203.4 MB.
    char* w = (char*)d_ws;
    _Float16* xh    = (_Float16*)(w);                       // 50,331,648 B
    _Float16* attn  = xh;                                   // alias
    _Float16* Wqkvt = (_Float16*)(w + 50331648);            //  1,572,864 B (Wq|Wk|Wv)^T
    _Float16* Wot   = (_Float16*)(w + 51904512);            //    524,288 B
    _Float16* qb    = (_Float16*)(w + 52428800);            // 50,331,648 B
    _Float16* kb    = (_Float16*)(w + 102760448);           // 50,331,648 B
    _Float16* vtb   = (_Float16*)(w + 153092096);           // 50,331,648 B -> end 203,423,744

    k_cvt_x<<<12288, 256, 0, stream>>>(x, xh);
    dim3 tg(16, 16);
    k_transpose_w<<<tg, 256, 0, stream>>>(Wq, Wqkvt);
    k_transpose_w<<<tg, 256, 0, stream>>>(Wk, Wqkvt + 512 * EMB);
    k_transpose_w<<<tg, 256, 0, stream>>>(Wv, Wqkvt + 1024 * EMB);
    k_transpose_w<<<tg, 256, 0, stream>>>(Wo, Wot);
    k_qkv<<<4608, 256, 0, stream>>>(xh, Wqkvt, bq, bk, bv, qb, kb, vtb);
    k_core<<<1536, 256, 0, stream>>>(qb, kb, vtb, attn);
    k_out<<<1536, 256, 0, stream>>>(attn, Wot, bo, out);
}

// Round 3
// 378.650 us; speedup vs baseline: 1.0863x; 1.0175x over previous
//
#include <hip/hip_runtime.h>
#include <hip/hip_bf16.h>
#include <cstdint>

// B=384, S=128, E=512, H=4, D=128. out = softmax((x Wq)(x Wk)^T) (x Wv) Wo
// Round 3: XCD-aware swizzles (x band stays on one XCD's L2), k_core with zero
// staging (Q/K/V^T direct from global, LDS only for P/O round-trip, 32 KB),
// k_qkv epilogue via LDS round-trip (b128 stores), prep fused into one launch.

#define EMB 512

typedef __attribute__((ext_vector_type(4))) float    f32x4;
typedef __attribute__((ext_vector_type(8))) _Float16 f16x8;

#define MFMA16(a, b, c) __builtin_amdgcn_mfma_f32_16x16x32_f16((a), (b), (c), 0, 0, 0)

// XOR swizzle: element (row,col) of a [*][stride] f16 tile at
// row*stride + (col ^ (((row>>2)&3)<<4)). C-writebacks conflict-free,
// b128 fragment reads conflict-ideal despite stride % 128B == 0.
__device__ __forceinline__ int swz128(int row, int col) {
    return row * 128 + (col ^ (((row >> 2) & 3) << 4));
}
__device__ __forceinline__ int swz64(int row, int col) {
    return row * 64 + (col ^ (((row >> 2) & 3) << 4));
}

__device__ __forceinline__ void gld_lds16(const _Float16* g, _Float16* l) {
    __builtin_amdgcn_global_load_lds(
        (const __attribute__((address_space(1))) void*)g,
        (__attribute__((address_space(3))) void*)l, 16, 0, 0);
}

// Stage a [128][64] f16 tile (row stride 64) from global rows grow0+n,
// cols [k0,k0+64), stride EMB. Swizzle applied via the source gather.
__device__ __forceinline__ void stage64(_Float16* lds, const _Float16* gbase,
                                        int grow0, int k0, int wave, int lane) {
#pragma unroll
    for (int i = 0; i < 4; ++i) {
        int idx = wave * 256 + i * 64 + lane;   // 16B-block id, 0..1023
        int n   = idx >> 3;
        int kb  = (idx & 7) ^ (((n >> 2) & 3) << 1);
        gld_lds16(gbase + (grow0 + n) * EMB + k0 + kb * 8,
                  lds + wave * 2048 + i * 512);
    }
}

#define ZACC(A)                                   \
    _Pragma("unroll") for (int _i = 0; _i < 2; ++_i) \
    _Pragma("unroll") for (int _j = 0; _j < 8; ++_j) \
        A[_i][_j] = (f32x4){0.f, 0.f, 0.f, 0.f};

// ---------------- prep: x->f16 + 4 weight transposes, one launch ----------------
__global__ void k_prep(const float* __restrict__ x, _Float16* __restrict__ xh,
                       const float* __restrict__ Wq, const float* __restrict__ Wk,
                       const float* __restrict__ Wv, const float* __restrict__ Wo,
                       _Float16* __restrict__ Wqkvt, _Float16* __restrict__ Wot) {
    __shared__ float t[32][33];
    const int g = blockIdx.x, tid = threadIdx.x;
    if (g < 12288) {
        long i = ((long)g * 256 + tid) * 8;
        f32x4 a = *(const f32x4*)(x + i);
        f32x4 b = *(const f32x4*)(x + i + 4);
        f16x8 o;
        o[0] = (_Float16)a[0]; o[1] = (_Float16)a[1];
        o[2] = (_Float16)a[2]; o[3] = (_Float16)a[3];
        o[4] = (_Float16)b[0]; o[5] = (_Float16)b[1];
        o[6] = (_Float16)b[2]; o[7] = (_Float16)b[3];
        *(f16x8*)(xh + i) = o;
        return;
    }
    const int tb = g - 12288;            // 0..1023
    const int z = tb >> 8, t2 = tb & 255;
    const float* W = (z == 0) ? Wq : (z == 1) ? Wk : (z == 2) ? Wv : Wo;
    _Float16* Wt = (z < 3) ? (Wqkvt + (long)z * 512 * EMB) : Wot;
    const int tx = tid & 31, ty = tid >> 5;      // 32 x 8
    const int k0 = (t2 & 15) * 32, n0 = (t2 >> 4) * 32;
#pragma unroll
    for (int i = 0; i < 4; ++i)
        t[ty + i * 8][tx] = W[(k0 + ty + i * 8) * EMB + n0 + tx];
    __syncthreads();
#pragma unroll
    for (int i = 0; i < 4; ++i)
        Wt[(n0 + ty + i * 8) * EMB + k0 + tx] = (_Float16)t[tx][ty + i * 8];
}

// ---------------- QKV projection GEMM ----------------
// C[49152 x 1536] = xh @ [Wq|Wk|Wv]. m-tile = batch bb, n-tile j: 0..3 Q head,
// 4..7 K head, 8..11 V head (operands SWAPPED -> V^T in C-layout for free).
// Block swizzle: all 12 j-tiles of a bb share g&7 -> same XCD -> x band
// fetched into one XCD's L2 only.
__global__ __launch_bounds__(256, 4)
void k_qkv(const _Float16* __restrict__ xh, const _Float16* __restrict__ Wqkvt,
           const float* __restrict__ bq, const float* __restrict__ bk,
           const float* __restrict__ bv,
           _Float16* __restrict__ qb, _Float16* __restrict__ kb,
           _Float16* __restrict__ vtb) {
    __shared__ _Float16 S[2][128 * 64];
    _Float16* SA = S[0];
    _Float16* SB = S[1];
    const int tid = threadIdx.x, wave = tid >> 6, lane = tid & 63;
    const int l15 = lane & 15, quad = lane >> 4;
    const int g = blockIdx.x;                    // 4608 = 8 xcd * (48 bb * 12 j)
    const int xcd = g & 7, r = g >> 3;
    const int bb = xcd * 48 + r / 12, j = r % 12;
    const int m0 = bb * 128;
    const bool vswap = (j >= 8);
    const _Float16* As = vswap ? SB : SA;
    const _Float16* Bs = vswap ? SA : SB;
    f32x4 acc[2][8];
    ZACC(acc);
    for (int k0 = 0; k0 < EMB; k0 += 64) {
        stage64(SA, xh, m0, k0, wave, lane);
        stage64(SB, Wqkvt, j * 128, k0, wave, lane);
        __syncthreads();
#pragma unroll
        for (int ktl = 0; ktl < 2; ++ktl) {
            int cb = ktl * 32 + quad * 8;
            f16x8 a0 = *(const f16x8*)&As[swz64(wave * 32 + l15, cb)];
            f16x8 a1 = *(const f16x8*)&As[swz64(wave * 32 + 16 + l15, cb)];
#pragma unroll
            for (int nt = 0; nt < 8; ++nt) {
                f16x8 bbf = *(const f16x8*)&Bs[swz64(nt * 16 + l15, cb)];
                acc[0][nt] = MFMA16(a0, bbf, acc[0][nt]);
                acc[1][nt] = MFMA16(a1, bbf, acc[1][nt]);
            }
        }
        __syncthreads();
    }
    // epilogue: C (+bias) -> LDS (32 KB, swizzled) -> coalesced b128 stores
    _Float16* SC = &S[0][0];
    if (!vswap) {
        const float* bias = (j < 4) ? bq : bk;
        const int nc0 = (j & 3) * 128;
#pragma unroll
        for (int nt = 0; nt < 8; ++nt) {
            int col = nt * 16 + l15;
            float bz = bias[nc0 + col];
#pragma unroll
            for (int mt = 0; mt < 2; ++mt)
#pragma unroll
                for (int rr = 0; rr < 4; ++rr) {
                    int row = wave * 32 + mt * 16 + quad * 4 + rr;
                    SC[swz128(row, col)] = (_Float16)(acc[mt][nt][rr] + bz);
                }
        }
        __syncthreads();
        _Float16* dst = (j < 4) ? qb : kb;
#pragma unroll
        for (int i = 0; i < 8; ++i) {
            int idx = i * 256 + tid;
            int row = idx >> 4, col = (idx & 15) * 8;
            f16x8 v = *(const f16x8*)&SC[row * 128 + (col ^ (((row >> 2) & 3) << 4))];
            *(f16x8*)(dst + (long)(m0 + row) * EMB + nc0 + col) = v;
        }
    } else {
        const int hv = j - 8;
#pragma unroll
        for (int mt = 0; mt < 2; ++mt)
#pragma unroll
            for (int rr = 0; rr < 4; ++rr) {
                int row = wave * 32 + mt * 16 + quad * 4 + rr;   // row = head-dim d
                float bz = bv[hv * 128 + row];
#pragma unroll
                for (int nt = 0; nt < 8; ++nt) {
                    int col = nt * 16 + l15;                     // col = token t
                    SC[swz128(row, col)] = (_Float16)(acc[mt][nt][rr] + bz);
                }
            }
        __syncthreads();
        _Float16* dst = vtb + (long)(bb * 4 + hv) * 128 * 128;
#pragma unroll
        for (int i = 0; i < 8; ++i) {
            int idx = i * 256 + tid;
            int row = idx >> 4, col = (idx & 15) * 8;
            f16x8 v = *(const f16x8*)&SC[row * 128 + (col ^ (((row >> 2) & 3) << 4))];
            *(f16x8*)(dst + row * 128 + col) = v;
        }
    }
}

// ---------------- attention core: one block per (b,h), ZERO staging ----------------
// Q/K/V^T fragments read directly from global (L2-resident, 16 B/lane).
// LDS (32 KB) used only for the P and O C->A layout round-trips. 3 barriers.
// MFMA layouts: A[m=lane&15][k=quad*8+j], B[k=quad*8+j][n=lane&15],
// C/D: col=lane&15, row=quad*4+reg.
__global__ __launch_bounds__(256, 4)
void k_core(const _Float16* __restrict__ qb, const _Float16* __restrict__ kb,
            const _Float16* __restrict__ vtb, _Float16* __restrict__ attn) {
    __shared__ _Float16 SP[128 * 128];   // P -> O
    const int tid = threadIdx.x, wave = tid >> 6, lane = tid & 63;
    const int l15 = lane & 15, quad = lane >> 4;
    const int g = blockIdx.x;                    // 1536 = 8 xcd * (48 b * 4 h)
    const int xcd = g & 7, r = g >> 3;
    const int b = xcd * 48 + (r >> 2), h = r & 3;
    const int sRow0 = b * 128, wRow0 = h * 128;
    const _Float16* vt = vtb + (long)(b * 4 + h) * 128 * 128;
    f32x4 acc[2][8];

    // ---- scores = Q K^T, all operands direct from global
    ZACC(acc);
#pragma unroll
    for (int kt = 0; kt < 4; ++kt) {
        int ca = kt * 32 + quad * 8;
        const _Float16* qrow = qb + (long)(sRow0 + wave * 32 + l15) * EMB + wRow0 + ca;
        f16x8 q0 = *(const f16x8*)qrow;
        f16x8 q1 = *(const f16x8*)(qrow + 16 * EMB);
#pragma unroll
        for (int nt = 0; nt < 8; ++nt) {
            f16x8 kf = *(const f16x8*)(kb + (long)(sRow0 + nt * 16 + l15) * EMB + wRow0 + ca);
            acc[0][nt] = MFMA16(q0, kf, acc[0][nt]);
            acc[1][nt] = MFMA16(q1, kf, acc[1][nt]);
        }
    }
    // ---- softmax over t (row spread across the 16 lanes of a quad-row)
#pragma unroll
    for (int mt = 0; mt < 2; ++mt)
#pragma unroll
        for (int rr = 0; rr < 4; ++rr) {
            float mx = acc[mt][0][rr];
#pragma unroll
            for (int nt = 1; nt < 8; ++nt) mx = fmaxf(mx, acc[mt][nt][rr]);
            mx = fmaxf(mx, __shfl_xor(mx, 1));
            mx = fmaxf(mx, __shfl_xor(mx, 2));
            mx = fmaxf(mx, __shfl_xor(mx, 4));
            mx = fmaxf(mx, __shfl_xor(mx, 8));
            float sm = 0.f;
#pragma unroll
            for (int nt = 0; nt < 8; ++nt) {
                float e = __expf(acc[mt][nt][rr] - mx);
                acc[mt][nt][rr] = e;
                sm += e;
            }
            sm += __shfl_xor(sm, 1);
            sm += __shfl_xor(sm, 2);
            sm += __shfl_xor(sm, 4);
            sm += __shfl_xor(sm, 8);
            float inv = 1.0f / sm;
#pragma unroll
            for (int nt = 0; nt < 8; ++nt) acc[mt][nt][rr] *= inv;
        }

    // ---- P -> SP (C-layout -> A-layout via LDS)
#pragma unroll
    for (int mt = 0; mt < 2; ++mt)
#pragma unroll
        for (int nt = 0; nt < 8; ++nt) {
            int col = nt * 16 + l15;
#pragma unroll
            for (int rr = 0; rr < 4; ++rr) {
                int row = wave * 32 + mt * 16 + quad * 4 + rr;
                SP[swz128(row, col)] = (_Float16)acc[mt][nt][rr];
            }
        }
    __syncthreads();

    // ---- O = P @ V  (A from SP; B[k=t][n=d] = V^T row d from global)
    ZACC(acc);
#pragma unroll
    for (int kt = 0; kt < 4; ++kt) {
        int ca = kt * 32 + quad * 8;
        int rp = wave * 32 + l15;
        f16x8 p0 = *(const f16x8*)&SP[swz128(rp, ca)];
        f16x8 p1 = *(const f16x8*)&SP[swz128(rp + 16, ca)];
#pragma unroll
        for (int nt = 0; nt < 8; ++nt) {
            f16x8 vf = *(const f16x8*)(vt + (nt * 16 + l15) * 128 + ca);
            acc[0][nt] = MFMA16(p0, vf, acc[0][nt]);
            acc[1][nt] = MFMA16(p1, vf, acc[1][nt]);
        }
    }
    __syncthreads();   // all P reads done before overwriting SP

    // ---- O -> SP, then coalesced b128 stores
#pragma unroll
    for (int mt = 0; mt < 2; ++mt)
#pragma unroll
        for (int nt = 0; nt < 8; ++nt) {
            int col = nt * 16 + l15;
#pragma unroll
            for (int rr = 0; rr < 4; ++rr) {
                int row = wave * 32 + mt * 16 + quad * 4 + rr;
                SP[swz128(row, col)] = (_Float16)acc[mt][nt][rr];
            }
        }
    __syncthreads();
#pragma unroll
    for (int i = 0; i < 8; ++i) {
        int idx = i * 256 + tid;
        int row = idx >> 4, col = (idx & 15) * 8;
        f16x8 v = *(const f16x8*)&SP[row * 128 + (col ^ (((row >> 2) & 3) << 4))];
        *(f16x8*)(attn + (long)(sRow0 + row) * EMB + wRow0 + col) = v;
    }
}

// ---------------- output projection: out = attn @ Wo + bo (fp32) ----------------
__global__ __launch_bounds__(256, 4)
void k_out(const _Float16* __restrict__ attn, const _Float16* __restrict__ Wot,
           const float* __restrict__ bo, float* __restrict__ out) {
    __shared__ _Float16 SA[128 * 64];
    __shared__ _Float16 SB[128 * 64];
    const int tid = threadIdx.x, wave = tid >> 6, lane = tid & 63;
    const int l15 = lane & 15, quad = lane >> 4;
    const int g = blockIdx.x;                    // 1536 = 8 xcd * (48 m * 4 n)
    const int xcd = g & 7, r = g >> 3;
    const int m0 = (xcd * 48 + (r >> 2)) * 128, n0 = (r & 3) * 128;
    f32x4 acc[2][8];
    ZACC(acc);
    for (int k0 = 0; k0 < EMB; k0 += 64) {
        stage64(SA, attn, m0, k0, wave, lane);
        stage64(SB, Wot, n0, k0, wave, lane);
        __syncthreads();
#pragma unroll
        for (int ktl = 0; ktl < 2; ++ktl) {
            int ra = wave * 32 + l15;
            int cb = ktl * 32 + quad * 8;
            f16x8 a0 = *(const f16x8*)&SA[swz64(ra, cb)];
            f16x8 a1 = *(const f16x8*)&SA[swz64(ra + 16, cb)];
#pragma unroll
            for (int nt = 0; nt < 8; ++nt) {
                f16x8 bb = *(const f16x8*)&SB[swz64(nt * 16 + l15, cb)];
                acc[0][nt] = MFMA16(a0, bb, acc[0][nt]);
                acc[1][nt] = MFMA16(a1, bb, acc[1][nt]);
            }
        }
        __syncthreads();
    }
#pragma unroll
    for (int nt = 0; nt < 8; ++nt) {
        int col = n0 + nt * 16 + l15;
        float bias = bo[col];
#pragma unroll
        for (int mt = 0; mt < 2; ++mt)
#pragma unroll
            for (int rr = 0; rr < 4; ++rr) {
                int row = m0 + wave * 32 + mt * 16 + quad * 4 + rr;
                out[(long)row * EMB + col] = acc[mt][nt][rr] + bias;
            }
    }
}

extern "C" void kernel_launch(void* const* d_in, const int* in_sizes, int n_in,
                              void* d_out, int out_size, void* d_ws, size_t ws_size,
                              hipStream_t stream) {
    const float* x  = (const float*)d_in[0];
    const float* Wq = (const float*)d_in[1];
    const float* bq = (const float*)d_in[2];
    const float* Wk = (const float*)d_in[3];
    const float* bk = (const float*)d_in[4];
    const float* Wv = (const float*)d_in[5];
    const float* bv = (const float*)d_in[6];
    const float* Wo = (const float*)d_in[7];
    const float* bo = (const float*)d_in[8];
    float* out = (float*)d_out;

    // ws layout (bytes). attn ALIASES xh (xh dead after k_qkv). Peak ~203.4 MB.
    char* w = (char*)d_ws;
    _Float16* xh    = (_Float16*)(w);                       // 50,331,648 B
    _Float16* attn  = xh;                                   // alias
    _Float16* Wqkvt = (_Float16*)(w + 50331648);            //  1,572,864 B (Wq|Wk|Wv)^T
    _Float16* Wot   = (_Float16*)(w + 51904512);            //    524,288 B
    _Float16* qb    = (_Float16*)(w + 52428800);            // 50,331,648 B
    _Float16* kb    = (_Float16*)(w + 102760448);           // 50,331,648 B
    _Float16* vtb   = (_Float16*)(w + 153092096);           // 50,331,648 B -> end 203,423,744

    k_prep<<<13312, 256, 0, stream>>>(x, xh, Wq, Wk, Wv, Wo, Wqkvt, Wot);
    k_qkv<<<4608, 256, 0, stream>>>(xh, Wqkvt, bq, bk, bv, qb, kb, vtb);
    k_core<<<1536, 256, 0, stream>>>(qb, kb, vtb, attn);
    k_out<<<1536, 256, 0, stream>>>(attn, Wot, bo, out);
}

// Round 4
// 370.100 us; speedup vs baseline: 1.1114x; 1.0231x over previous
//
#include <hip/hip_runtime.h>
#include <hip/hip_bf16.h>
#include <cstdint>

// B=384, S=128, E=512, H=4, D=128. out = softmax((x Wq)(x Wk)^T) (x Wv) Wo
// Round 4: k_qkv at m97 plateau (831 TF) - unchanged. Restructured k_core
// (staged K/V, 512-thread blocks, 16 waves/CU) and k_out (64x128 tiles,
// 3072 blocks = 12/CU, fp32 LDS-round-trip epilogue -> coalesced f32x4 stores).

#define EMB 512

typedef __attribute__((ext_vector_type(4))) float    f32x4;
typedef __attribute__((ext_vector_type(8))) _Float16 f16x8;

#define MFMA16(a, b, c) __builtin_amdgcn_mfma_f32_16x16x32_f16((a), (b), (c), 0, 0, 0)

// XOR swizzle: element (row,col) of a [*][stride] f16 tile at
// row*stride + (col ^ (((row>>2)&3)<<4)). C-writebacks conflict-free,
// b128 fragment reads conflict-ideal despite stride % 128B == 0.
__device__ __forceinline__ int swz128(int row, int col) {
    return row * 128 + (col ^ (((row >> 2) & 3) << 4));
}
__device__ __forceinline__ int swz64(int row, int col) {
    return row * 64 + (col ^ (((row >> 2) & 3) << 4));
}

__device__ __forceinline__ void gld_lds16(const _Float16* g, _Float16* l) {
    __builtin_amdgcn_global_load_lds(
        (const __attribute__((address_space(1))) void*)g,
        (__attribute__((address_space(3))) void*)l, 16, 0, 0);
}

// Stage a [128][64] f16 tile (row stride 64) from global rows grow0+n,
// cols [k0,k0+64), stride EMB. Swizzle applied via the source gather.
__device__ __forceinline__ void stage64(_Float16* lds, const _Float16* gbase,
                                        int grow0, int k0, int wave, int lane) {
#pragma unroll
    for (int i = 0; i < 4; ++i) {
        int idx = wave * 256 + i * 64 + lane;   // 16B-block id, 0..1023
        int n   = idx >> 3;
        int kb  = (idx & 7) ^ (((n >> 2) & 3) << 1);
        gld_lds16(gbase + (grow0 + n) * EMB + k0 + kb * 8,
                  lds + wave * 2048 + i * 512);
    }
}

#define ZACC(A)                                   \
    _Pragma("unroll") for (int _i = 0; _i < 2; ++_i) \
    _Pragma("unroll") for (int _j = 0; _j < 8; ++_j) \
        A[_i][_j] = (f32x4){0.f, 0.f, 0.f, 0.f};

// ---------------- prep: x->f16 + 4 weight transposes, one launch ----------------
__global__ void k_prep(const float* __restrict__ x, _Float16* __restrict__ xh,
                       const float* __restrict__ Wq, const float* __restrict__ Wk,
                       const float* __restrict__ Wv, const float* __restrict__ Wo,
                       _Float16* __restrict__ Wqkvt, _Float16* __restrict__ Wot) {
    __shared__ float t[32][33];
    const int g = blockIdx.x, tid = threadIdx.x;
    if (g < 12288) {
        long i = ((long)g * 256 + tid) * 8;
        f32x4 a = *(const f32x4*)(x + i);
        f32x4 b = *(const f32x4*)(x + i + 4);
        f16x8 o;
        o[0] = (_Float16)a[0]; o[1] = (_Float16)a[1];
        o[2] = (_Float16)a[2]; o[3] = (_Float16)a[3];
        o[4] = (_Float16)b[0]; o[5] = (_Float16)b[1];
        o[6] = (_Float16)b[2]; o[7] = (_Float16)b[3];
        *(f16x8*)(xh + i) = o;
        return;
    }
    const int tb = g - 12288;            // 0..1023
    const int z = tb >> 8, t2 = tb & 255;
    const float* W = (z == 0) ? Wq : (z == 1) ? Wk : (z == 2) ? Wv : Wo;
    _Float16* Wt = (z < 3) ? (Wqkvt + (long)z * 512 * EMB) : Wot;
    const int tx = tid & 31, ty = tid >> 5;      // 32 x 8
    const int k0 = (t2 & 15) * 32, n0 = (t2 >> 4) * 32;
#pragma unroll
    for (int i = 0; i < 4; ++i)
        t[ty + i * 8][tx] = W[(k0 + ty + i * 8) * EMB + n0 + tx];
    __syncthreads();
#pragma unroll
    for (int i = 0; i < 4; ++i)
        Wt[(n0 + ty + i * 8) * EMB + k0 + tx] = (_Float16)t[tx][ty + i * 8];
}

// ---------------- QKV projection GEMM (UNCHANGED - at m97 plateau) ----------------
__global__ __launch_bounds__(256, 4)
void k_qkv(const _Float16* __restrict__ xh, const _Float16* __restrict__ Wqkvt,
           const float* __restrict__ bq, const float* __restrict__ bk,
           const float* __restrict__ bv,
           _Float16* __restrict__ qb, _Float16* __restrict__ kb,
           _Float16* __restrict__ vtb) {
    __shared__ _Float16 S[2][128 * 64];
    _Float16* SA = S[0];
    _Float16* SB = S[1];
    const int tid = threadIdx.x, wave = tid >> 6, lane = tid & 63;
    const int l15 = lane & 15, quad = lane >> 4;
    const int g = blockIdx.x;                    // 4608 = 8 xcd * (48 bb * 12 j)
    const int xcd = g & 7, r = g >> 3;
    const int bb = xcd * 48 + r / 12, j = r % 12;
    const int m0 = bb * 128;
    const bool vswap = (j >= 8);
    const _Float16* As = vswap ? SB : SA;
    const _Float16* Bs = vswap ? SA : SB;
    f32x4 acc[2][8];
    ZACC(acc);
    for (int k0 = 0; k0 < EMB; k0 += 64) {
        stage64(SA, xh, m0, k0, wave, lane);
        stage64(SB, Wqkvt, j * 128, k0, wave, lane);
        __syncthreads();
#pragma unroll
        for (int ktl = 0; ktl < 2; ++ktl) {
            int cb = ktl * 32 + quad * 8;
            f16x8 a0 = *(const f16x8*)&As[swz64(wave * 32 + l15, cb)];
            f16x8 a1 = *(const f16x8*)&As[swz64(wave * 32 + 16 + l15, cb)];
#pragma unroll
            for (int nt = 0; nt < 8; ++nt) {
                f16x8 bbf = *(const f16x8*)&Bs[swz64(nt * 16 + l15, cb)];
                acc[0][nt] = MFMA16(a0, bbf, acc[0][nt]);
                acc[1][nt] = MFMA16(a1, bbf, acc[1][nt]);
            }
        }
        __syncthreads();
    }
    // epilogue: C (+bias) -> LDS (32 KB, swizzled) -> coalesced b128 stores
    _Float16* SC = &S[0][0];
    if (!vswap) {
        const float* bias = (j < 4) ? bq : bk;
        const int nc0 = (j & 3) * 128;
#pragma unroll
        for (int nt = 0; nt < 8; ++nt) {
            int col = nt * 16 + l15;
            float bz = bias[nc0 + col];
#pragma unroll
            for (int mt = 0; mt < 2; ++mt)
#pragma unroll
                for (int rr = 0; rr < 4; ++rr) {
                    int row = wave * 32 + mt * 16 + quad * 4 + rr;
                    SC[swz128(row, col)] = (_Float16)(acc[mt][nt][rr] + bz);
                }
        }
        __syncthreads();
        _Float16* dst = (j < 4) ? qb : kb;
#pragma unroll
        for (int i = 0; i < 8; ++i) {
            int idx = i * 256 + tid;
            int row = idx >> 4, col = (idx & 15) * 8;
            f16x8 v = *(const f16x8*)&SC[row * 128 + (col ^ (((row >> 2) & 3) << 4))];
            *(f16x8*)(dst + (long)(m0 + row) * EMB + nc0 + col) = v;
        }
    } else {
        const int hv = j - 8;
#pragma unroll
        for (int mt = 0; mt < 2; ++mt)
#pragma unroll
            for (int rr = 0; rr < 4; ++rr) {
                int row = wave * 32 + mt * 16 + quad * 4 + rr;   // row = head-dim d
                float bz = bv[hv * 128 + row];
#pragma unroll
                for (int nt = 0; nt < 8; ++nt) {
                    int col = nt * 16 + l15;                     // col = token t
                    SC[swz128(row, col)] = (_Float16)(acc[mt][nt][rr] + bz);
                }
            }
        __syncthreads();
        _Float16* dst = vtb + (long)(bb * 4 + hv) * 128 * 128;
#pragma unroll
        for (int i = 0; i < 8; ++i) {
            int idx = i * 256 + tid;
            int row = idx >> 4, col = (idx & 15) * 8;
            f16x8 v = *(const f16x8*)&SC[row * 128 + (col ^ (((row >> 2) & 3) << 4))];
            *(f16x8*)(dst + row * 128 + col) = v;
        }
    }
}

// ---------------- attention core: one 512-thread block per (b,h) ----------------
// K and V^T staged via global_load_lds (stream path); Q direct from global
// (one load per fragment). 8 waves/block, 64 KB LDS -> 2 blocks/CU = 16 waves.
// Each wave owns 16 score rows. 5 barriers total.
__global__ __launch_bounds__(512, 4)
void k_core(const _Float16* __restrict__ qb, const _Float16* __restrict__ kb,
            const _Float16* __restrict__ vtb, _Float16* __restrict__ attn) {
    __shared__ _Float16 SK[128 * 128];   // K -> P
    __shared__ _Float16 SV[128 * 128];   // V^T -> O
    const int tid = threadIdx.x, wave = tid >> 6, lane = tid & 63;
    const int l15 = lane & 15, quad = lane >> 4;
    const int g = blockIdx.x;                    // 1536 = 8 xcd * (48 b * 4 h)
    const int xcd = g & 7, r = g >> 3;
    const int b = xcd * 48 + (r >> 2), h = r & 3;
    const int sRow0 = b * 128, wRow0 = h * 128;
    const _Float16* vt = vtb + (long)(b * 4 + h) * 128 * 128;

    // stage K[t][d] and V^T[d][t] (2048 16B-blocks each, 8 waves x 4 iters)
#pragma unroll
    for (int i = 0; i < 4; ++i) {
        int seg = i * 8 + wave;                  // 0..31
        int idx = seg * 64 + lane;               // 0..2047
        int n   = idx >> 4;
        int kbk = (idx & 15) ^ (((n >> 2) & 3) << 1);
        gld_lds16(kb + (long)(sRow0 + n) * EMB + wRow0 + kbk * 8, SK + seg * 512);
        gld_lds16(vt + n * 128 + kbk * 8, SV + seg * 512);
    }
    __syncthreads();

    f32x4 acc[8];
#pragma unroll
    for (int nt = 0; nt < 8; ++nt) acc[nt] = (f32x4){0.f, 0.f, 0.f, 0.f};

    // ---- scores = Q K^T (wave owns rows wave*16..+16)
#pragma unroll
    for (int kt = 0; kt < 4; ++kt) {
        int ca = kt * 32 + quad * 8;
        f16x8 q0 = *(const f16x8*)(qb + (long)(sRow0 + wave * 16 + l15) * EMB + wRow0 + ca);
#pragma unroll
        for (int nt = 0; nt < 8; ++nt) {
            f16x8 kf = *(const f16x8*)&SK[swz128(nt * 16 + l15, ca)];
            acc[nt] = MFMA16(q0, kf, acc[nt]);
        }
    }
    // ---- softmax over t (row in the 16 lanes of a quad-row)
#pragma unroll
    for (int rr = 0; rr < 4; ++rr) {
        float mx = acc[0][rr];
#pragma unroll
        for (int nt = 1; nt < 8; ++nt) mx = fmaxf(mx, acc[nt][rr]);
        mx = fmaxf(mx, __shfl_xor(mx, 1));
        mx = fmaxf(mx, __shfl_xor(mx, 2));
        mx = fmaxf(mx, __shfl_xor(mx, 4));
        mx = fmaxf(mx, __shfl_xor(mx, 8));
        float sm = 0.f;
#pragma unroll
        for (int nt = 0; nt < 8; ++nt) {
            float e = __expf(acc[nt][rr] - mx);
            acc[nt][rr] = e;
            sm += e;
        }
        sm += __shfl_xor(sm, 1);
        sm += __shfl_xor(sm, 2);
        sm += __shfl_xor(sm, 4);
        sm += __shfl_xor(sm, 8);
        float inv = 1.0f / sm;
#pragma unroll
        for (int nt = 0; nt < 8; ++nt) acc[nt][rr] *= inv;
    }
    __syncthreads();   // all QK^T reads of SK done

    // ---- P -> SK (C-layout -> A-layout via LDS)
#pragma unroll
    for (int nt = 0; nt < 8; ++nt) {
        int col = nt * 16 + l15;
#pragma unroll
        for (int rr = 0; rr < 4; ++rr)
            SK[swz128(wave * 16 + quad * 4 + rr, col)] = (_Float16)acc[nt][rr];
    }
    __syncthreads();

    // ---- O = P @ V  (B[k=t][n=d] = SV row d, contiguous t)
#pragma unroll
    for (int nt = 0; nt < 8; ++nt) acc[nt] = (f32x4){0.f, 0.f, 0.f, 0.f};
#pragma unroll
    for (int kt = 0; kt < 4; ++kt) {
        int ca = kt * 32 + quad * 8;
        f16x8 p0 = *(const f16x8*)&SK[swz128(wave * 16 + l15, ca)];
#pragma unroll
        for (int nt = 0; nt < 8; ++nt) {
            f16x8 vf = *(const f16x8*)&SV[swz128(nt * 16 + l15, ca)];
            acc[nt] = MFMA16(p0, vf, acc[nt]);
        }
    }
    __syncthreads();   // all PV reads of SV done

    // ---- O -> SV, then coalesced b128 stores
#pragma unroll
    for (int nt = 0; nt < 8; ++nt) {
        int col = nt * 16 + l15;
#pragma unroll
        for (int rr = 0; rr < 4; ++rr)
            SV[swz128(wave * 16 + quad * 4 + rr, col)] = (_Float16)acc[nt][rr];
    }
    __syncthreads();
#pragma unroll
    for (int i = 0; i < 4; ++i) {
        int idx = i * 512 + tid;
        int row = idx >> 4, col = (idx & 15) * 8;
        f16x8 v = *(const f16x8*)&SV[row * 128 + (col ^ (((row >> 2) & 3) << 4))];
        *(f16x8*)(attn + (long)(sRow0 + row) * EMB + wRow0 + col) = v;
    }
}

// ---------------- output projection: out = attn @ Wo + bo (fp32) ----------------
// 64x128 tiles -> 3072 blocks = 12/CU (block-level pipelining of the staging
// loop). Epilogue: fp32 via LDS (quad-parity xor swizzle) -> coalesced f32x4.
__global__ __launch_bounds__(256, 4)
void k_out(const _Float16* __restrict__ attn, const _Float16* __restrict__ Wot,
           const float* __restrict__ bo, float* __restrict__ out) {
    __shared__ _Float16 SH[16384];               // 32 KB: A(8K)+B(16K) / fp32 64x128
    _Float16* SA = SH;
    _Float16* SB = SH + 4096;
    const int tid = threadIdx.x, wave = tid >> 6, lane = tid & 63;
    const int l15 = lane & 15, quad = lane >> 4;
    const int g = blockIdx.x;                    // 3072 = 8 xcd * (96 m * 4 n)
    const int xcd = g & 7, r = g >> 3;
    const int m0 = (xcd * 96 + (r >> 2)) * 64, n0 = (r & 3) * 128;
    f32x4 acc[8];
#pragma unroll
    for (int nt = 0; nt < 8; ++nt) acc[nt] = (f32x4){0.f, 0.f, 0.f, 0.f};
    for (int k0 = 0; k0 < EMB; k0 += 64) {
        // A: 64x64 (512 16B-blocks), B: 128x64 (1024 blocks)
#pragma unroll
        for (int i = 0; i < 2; ++i) {
            int seg = i * 4 + wave;
            int idx = seg * 64 + lane;
            int n = idx >> 3, kbk = (idx & 7) ^ (((n >> 2) & 3) << 1);
            gld_lds16(attn + (long)(m0 + n) * EMB + k0 + kbk * 8, SA + seg * 512);
        }
#pragma unroll
        for (int i = 0; i < 4; ++i) {
            int seg = i * 4 + wave;
            int idx = seg * 64 + lane;
            int n = idx >> 3, kbk = (idx & 7) ^ (((n >> 2) & 3) << 1);
            gld_lds16(Wot + (long)(n0 + n) * EMB + k0 + kbk * 8, SB + seg * 512);
        }
        __syncthreads();
#pragma unroll
        for (int ktl = 0; ktl < 2; ++ktl) {
            int cb = ktl * 32 + quad * 8;
            f16x8 a0 = *(const f16x8*)&SA[swz64(wave * 16 + l15, cb)];
#pragma unroll
            for (int nt = 0; nt < 8; ++nt) {
                f16x8 bb = *(const f16x8*)&SB[swz64(nt * 16 + l15, cb)];
                acc[nt] = MFMA16(a0, bb, acc[nt]);
            }
        }
        __syncthreads();
    }
    // epilogue: acc (+bias) -> fp32 LDS (quad-parity xor, 2-way = free) -> f32x4
    float* SF = (float*)SH;
#pragma unroll
    for (int nt = 0; nt < 8; ++nt) {
        int col = nt * 16 + l15;
        float bz = bo[n0 + col];
#pragma unroll
        for (int rr = 0; rr < 4; ++rr) {
            int row = wave * 16 + quad * 4 + rr;
            SF[row * 128 + (col ^ (((row >> 2) & 1) << 4))] = acc[nt][rr] + bz;
        }
    }
    __syncthreads();
#pragma unroll
    for (int i = 0; i < 8; ++i) {
        int idx = i * 256 + tid;
        int row = idx >> 5, c4 = (idx & 31) * 4;
        f32x4 v = *(const f32x4*)&SF[row * 128 + (c4 ^ (((row >> 2) & 1) << 4))];
        *(f32x4*)(out + (long)(m0 + row) * EMB + n0 + c4) = v;
    }
}

extern "C" void kernel_launch(void* const* d_in, const int* in_sizes, int n_in,
                              void* d_out, int out_size, void* d_ws, size_t ws_size,
                              hipStream_t stream) {
    const float* x  = (const float*)d_in[0];
    const float* Wq = (const float*)d_in[1];
    const float* bq = (const float*)d_in[2];
    const float* Wk = (const float*)d_in[3];
    const float* bk = (const float*)d_in[4];
    const float* Wv = (const float*)d_in[5];
    const float* bv = (const float*)d_in[6];
    const float* Wo = (const float*)d_in[7];
    const float* bo = (const float*)d_in[8];
    float* out = (float*)d_out;

    // ws layout (bytes). attn ALIASES xh (xh dead after k_qkv). Peak ~203.4 MB.
    char* w = (char*)d_ws;
    _Float16* xh    = (_Float16*)(w);                       // 50,331,648 B
    _Float16* attn  = xh;                                   // alias
    _Float16* Wqkvt = (_Float16*)(w + 50331648);            //  1,572,864 B (Wq|Wk|Wv)^T
    _Float16* Wot   = (_Float16*)(w + 51904512);            //    524,288 B
    _Float16* qb    = (_Float16*)(w + 52428800);            // 50,331,648 B
    _Float16* kb    = (_Float16*)(w + 102760448);           // 50,331,648 B
    _Float16* vtb   = (_Float16*)(w + 153092096);           // 50,331,648 B -> end 203,423,744

    k_prep<<<13312, 256, 0, stream>>>(x, xh, Wq, Wk, Wv, Wo, Wqkvt, Wot);
    k_qkv<<<4608, 256, 0, stream>>>(xh, Wqkvt, bq, bk, bv, qb, kb, vtb);
    k_core<<<1536, 512, 0, stream>>>(qb, kb, vtb, attn);
    k_out<<<3072, 256, 0, stream>>>(attn, Wot, bo, out);
}